// Round 6
// baseline (171.355 us; speedup 1.0000x reference)
//
#include <hip/hip_runtime.h>
#include <hip/hip_bf16.h>
#include <math.h>

#define NCLS 10
#define NTOT 8192
#define NTIL 64        // 128-row panels per side
#define NBLKS 544      // sum_{it} (16 - it/4) strip blocks (8 x 68)
#define NS 64          // partial slots per row (packed col+row ranges)

using short8 = __attribute__((ext_vector_type(8))) short;
using f32x4  = __attribute__((ext_vector_type(4))) float;

__device__ __forceinline__ float digammaf_dev(float x) {
    float r = 0.0f;
    while (x < 6.0f) { r -= 1.0f / x; x += 1.0f; }
    float inv = 1.0f / x;
    float inv2 = inv * inv;
    float s = logf(x) - 0.5f * inv
            - inv2 * (0.083333333333f - inv2 * (0.0083333333333f - inv2 * 0.0039682539683f));
    return r + s;
}

__device__ __forceinline__ void cmpswap(float& a, float& b) {
    float lo = fminf(a, b), hi = fmaxf(a, b);
    a = lo; b = hi;
}

// branchless insert of v into ascending quad, keep 4 smallest
__device__ __forceinline__ void ins7(float v, float& b0, float& b1, float& b2, float& b3) {
    float x0 = fminf(b0, v); float c0 = fmaxf(b0, v);
    float x1 = fminf(b1, c0); float c1 = fmaxf(b1, c0);
    float x2 = fminf(b2, c1); float c2 = fmaxf(b2, c1);
    float x3 = fminf(b3, c2);
    b0 = x0; b1 = x1; b2 = x2; b3 = x3;
}

// merge my sorted quad with lane^mk's sorted quad -> 4 smallest of union, sorted
__device__ __forceinline__ void bmerge(int mk, float& v0, float& v1, float& v2, float& v3) {
    float u0 = __shfl_xor(v0, mk), u1 = __shfl_xor(v1, mk);
    float u2 = __shfl_xor(v2, mk), u3 = __shfl_xor(v3, mk);
    float m0 = fminf(v0, u3), m1 = fminf(v1, u2);
    float m2 = fminf(v2, u1), m3 = fminf(v3, u0);
    cmpswap(m0, m2); cmpswap(m1, m3);
    cmpswap(m0, m1); cmpswap(m2, m3);
    v0 = m0; v1 = m1; v2 = m2; v3 = m3;
}

__device__ __forceinline__ void gload_lds16(const void* g, void* s) {
    __builtin_amdgcn_global_load_lds((const __attribute__((address_space(1))) void*)g,
                                     (__attribute__((address_space(3))) void*)s, 16, 0, 0);
}

__global__ void zero_kernel(int* cls) {
    if (threadIdx.x < 16) cls[threadIdx.x] = 0;
}

// per row: sq (fp32), XS[row][0..127]=hi(bf16), [128..255]=lo(bf16)
__global__ void prep_kernel(const float* __restrict__ X,
                            float* __restrict__ sq, unsigned short* __restrict__ XS) {
    int wave = threadIdx.x >> 6, lane = threadIdx.x & 63;
    int row = blockIdx.x * 4 + wave;
    float2 v = *(const float2*)(X + (size_t)row * 128 + lane * 2);
    __hip_bfloat16 h0 = __float2bfloat16(v.x);
    __hip_bfloat16 h1 = __float2bfloat16(v.y);
    float hf0 = __bfloat162float(h0), hf1 = __bfloat162float(h1);
    __hip_bfloat16 l0 = __float2bfloat16(v.x - hf0);
    __hip_bfloat16 l1 = __float2bfloat16(v.y - hf1);
    ushort2 hp, lp;
    hp.x = *(unsigned short*)&h0; hp.y = *(unsigned short*)&h1;
    lp.x = *(unsigned short*)&l0; lp.y = *(unsigned short*)&l1;
    *(ushort2*)(XS + (size_t)row * 256 + lane * 2) = hp;
    *(ushort2*)(XS + (size_t)row * 256 + 128 + lane * 2) = lp;
    float s = fmaf(v.x, v.x, v.y * v.y);
    #pragma unroll
    for (int off = 32; off > 0; off >>= 1) s += __shfl_down(s, off);
    if (lane == 0) sq[row] = s;
}

// Strip-triangular MFMA distance pass.
// Block = row panel `it` x up to 4 j-tiles (jt in [max(it,4s), 4s+3]).
// A (hi+lo, 4 panels of 16KB) LDS-resident per block; B single 16KB panel/stage.
// Per tile K-order: (A_hi0+A_lo0)*B_hi0, (A_hi1+A_lo1)*B_hi1, A_hi0*B_lo0, A_hi1*B_lo1.
// Row-side top4/counts run in registers across the strip; col-side merged per tile.
// Slot layout per row (panel p): col slots [0,p) from tiles (it<p); row slots
// [p, p+16-(p>>2)) packed as it + (s - (it>>2)).
template <int PASS>
__global__ __launch_bounds__(256, 2)
void pass_kernel(const unsigned short* __restrict__ XS, const int* __restrict__ y,
                 const float* __restrict__ sq, const float* __restrict__ anchor,
                 float* __restrict__ top4p, int* __restrict__ cntp) {
    __shared__ __align__(16) char smem[81920];   // A: 4x16K @0; B: 16K @65536

    const int t = threadIdx.x;
    const int w = t >> 6, l = t & 63;
    const int wr = w >> 1, wc = w & 1;
    const int lg = l >> 4, lo16 = l & 15;

    // XCD swizzle (544 = 8*68) then strip decode
    const int bid = blockIdx.x;
    const int wg = (bid & 7) * (NBLKS / 8) + (bid >> 3);
    int it = 0, rem = wg;
    while (rem >= 16 - (it >> 2)) { rem -= 16 - (it >> 2); ++it; }
    const int s = (it >> 2) + rem;
    const int ibase = it * 128;
    const int jt_lo = (4 * s < it) ? it : 4 * s;
    const int jt_hi = 4 * s + 3;

    float sqi[16]; int yi[16]; float anc_i[16];
    #pragma unroll
    for (int mi = 0; mi < 4; ++mi)
        #pragma unroll
        for (int r = 0; r < 4; ++r) {
            int row = ibase + wr * 64 + mi * 16 + lg * 4 + r;
            sqi[mi * 4 + r] = sq[row];
            if (PASS == 1) yi[mi * 4 + r] = y[row];
            else anc_i[mi * 4 + r] = anchor[row];
        }

    // LDS read byte-offsets (per-panel base added at use)
    const int swz = (lo16 & 7) << 4;
    unsigned aoff[2], boff[2];
    #pragma unroll
    for (int kk = 0; kk < 2; ++kk) {
        const int cA = (kk * 64 + lg * 16) ^ swz;
        aoff[kk] = (unsigned)((wr * 64 + lo16) * 128 + cA);
        boff[kk] = (unsigned)(65536 + (wc * 64 + lo16) * 128 + cA);
    }
    // staging source (pre-swizzled column)
    const int srow = w * 32 + (l >> 3);
    const int scol = ((l & 7) ^ (l >> 3)) << 3;
    const unsigned short* gsrc = XS + (size_t)srow * 256 + scol;

    // stage all 4 A panels (hi0,hi1,lo0,lo1) once
    {
        const unsigned short* gA = gsrc + (size_t)ibase * 256;
        #pragma unroll
        for (int p = 0; p < 4; ++p)
            #pragma unroll
            for (int q = 0; q < 4; ++q)
                gload_lds16(gA + p * 64 + (size_t)q * 8 * 256,
                            smem + p * 16384 + w * 4096 + q * 1024);
    }

    float tp0[16], tp1[16], tp2[16], tp3[16];
    int cnt16[16];
    #pragma unroll
    for (int c = 0; c < 16; ++c) {
        if (PASS == 1) { tp0[c] = 1e30f; tp1[c] = 1e30f; tp2[c] = 1e30f; tp3[c] = 1e30f; }
        else cnt16[c] = 0;
    }

    #pragma unroll 1
    for (int jt = jt_lo; jt <= jt_hi; ++jt) {
        const int jbase = jt * 128;
        const bool diag = (jt == it);

        float sqj[4]; int yj[4]; float anc_j[4];
        #pragma unroll
        for (int ni = 0; ni < 4; ++ni) {
            int col = jbase + wc * 64 + ni * 16 + lo16;
            sqj[ni] = sq[col];
            if (PASS == 1) yj[ni] = y[col];
            else anc_j[ni] = anchor[col];
        }

        f32x4 acc[4][4];
        f32x4 zz = {0.0f, 0.0f, 0.0f, 0.0f};
        #pragma unroll
        for (int mi = 0; mi < 4; ++mi)
            #pragma unroll
            for (int ni = 0; ni < 4; ++ni) acc[mi][ni] = zz;

        #pragma unroll
        for (int p = 0; p < 4; ++p) {
            {   // stage B panel p (kB = p*64 shorts: hi0,hi1,lo0,lo1)
                const unsigned short* gB = gsrc + (size_t)jbase * 256 + p * 64;
                char* Bb = smem + 65536 + w * 4096;
                #pragma unroll
                for (int q = 0; q < 4; ++q)
                    gload_lds16(gB + (size_t)q * 8 * 256, Bb + q * 1024);
            }
            __syncthreads();
            #pragma unroll
            for (int kk = 0; kk < 2; ++kk) {
                short8 bF[4];
                #pragma unroll
                for (int ni = 0; ni < 4; ++ni)
                    bF[ni] = *(const short8*)(smem + boff[kk] + ni * 2048);
                {
                    const int pa = (p < 2) ? p : (p - 2);   // A_hi partner
                    short8 aF[4];
                    #pragma unroll
                    for (int mi = 0; mi < 4; ++mi)
                        aF[mi] = *(const short8*)(smem + pa * 16384 + aoff[kk] + mi * 2048);
                    #pragma unroll
                    for (int mi = 0; mi < 4; ++mi)
                        #pragma unroll
                        for (int ni = 0; ni < 4; ++ni)
                            acc[mi][ni] = __builtin_amdgcn_mfma_f32_16x16x32_bf16(
                                aF[mi], bF[ni], acc[mi][ni], 0, 0, 0);
                }
                if (p < 2) {                                // A_lo partner (lo x hi)
                    short8 aF[4];
                    #pragma unroll
                    for (int mi = 0; mi < 4; ++mi)
                        aF[mi] = *(const short8*)(smem + (p + 2) * 16384 + aoff[kk] + mi * 2048);
                    #pragma unroll
                    for (int mi = 0; mi < 4; ++mi)
                        #pragma unroll
                        for (int ni = 0; ni < 4; ++ni)
                            acc[mi][ni] = __builtin_amdgcn_mfma_f32_16x16x32_bf16(
                                aF[mi], bF[ni], acc[mi][ni], 0, 0, 0);
                }
            }
            __syncthreads();
        }

        // per-tile epilogue
        if (PASS == 1) {
            float cq0[4], cq1[4], cq2[4], cq3[4];
            #pragma unroll
            for (int ni = 0; ni < 4; ++ni) {
                cq0[ni] = 1e30f; cq1[ni] = 1e30f; cq2[ni] = 1e30f; cq3[ni] = 1e30f;
            }
            #pragma unroll
            for (int mi = 0; mi < 4; ++mi)
                #pragma unroll
                for (int r = 0; r < 4; ++r) {
                    const int idx = mi * 4 + r;
                    #pragma unroll
                    for (int ni = 0; ni < 4; ++ni) {
                        float d2 = fmaf(-2.0f, acc[mi][ni][r], sqi[idx] + sqj[ni]);
                        d2 = fmaxf(d2, 0.0f);
                        float v = (yi[idx] == yj[ni]) ? d2 : 1e30f;
                        ins7(v, tp0[idx], tp1[idx], tp2[idx], tp3[idx]);
                        if (!diag) ins7(v, cq0[ni], cq1[ni], cq2[ni], cq3[ni]);
                    }
                }
            if (!diag) {
                float* scrC = (float*)(smem + 65536);   // [128][8] in B buffer
                #pragma unroll
                for (int ni = 0; ni < 4; ++ni) {
                    bmerge(16, cq0[ni], cq1[ni], cq2[ni], cq3[ni]);
                    bmerge(32, cq0[ni], cq1[ni], cq2[ni], cq3[ni]);
                    if (lg == 0) {
                        int cl = wc * 64 + ni * 16 + lo16;
                        float4 st; st.x = cq0[ni]; st.y = cq1[ni]; st.z = cq2[ni]; st.w = cq3[ni];
                        *(float4*)(scrC + cl * 8 + wr * 4) = st;
                    }
                }
                __syncthreads();
                if (t < 128) {
                    float4 qa = *(float4*)(scrC + t * 8);
                    float4 qb = *(float4*)(scrC + t * 8 + 4);
                    float b0 = qa.x, b1 = qa.y, b2 = qa.z, b3 = qa.w;
                    ins7(qb.x, b0, b1, b2, b3); ins7(qb.y, b0, b1, b2, b3);
                    ins7(qb.z, b0, b1, b2, b3); ins7(qb.w, b0, b1, b2, b3);
                    size_t base = ((size_t)(jbase + t) * NS + it) * 4;
                    top4p[base + 0] = b0; top4p[base + 1] = b1;
                    top4p[base + 2] = b2; top4p[base + 3] = b3;
                }
                __syncthreads();
            }
        } else {
            int cc[4] = {0, 0, 0, 0};
            #pragma unroll
            for (int mi = 0; mi < 4; ++mi)
                #pragma unroll
                for (int r = 0; r < 4; ++r) {
                    const int idx = mi * 4 + r;
                    int crow = 0;
                    #pragma unroll
                    for (int ni = 0; ni < 4; ++ni) {
                        float d2 = fmaf(-2.0f, acc[mi][ni][r], sqi[idx] + sqj[ni]);
                        d2 = fmaxf(d2, 0.0f);
                        crow += (d2 <= anc_i[idx]) ? 1 : 0;
                        if (!diag) cc[ni] += (d2 <= anc_j[ni]) ? 1 : 0;
                    }
                    cnt16[idx] += crow;
                }
            if (!diag) {
                int* scrI = (int*)(smem + 65536);   // [128][2] in B buffer
                #pragma unroll
                for (int ni = 0; ni < 4; ++ni) {
                    int c = cc[ni];
                    c += __shfl_xor(c, 16); c += __shfl_xor(c, 32);
                    if (lg == 0) scrI[(wc * 64 + ni * 16 + lo16) * 2 + wr] = c;
                }
                __syncthreads();
                if (t < 128) cntp[(size_t)(jbase + t) * NS + it] = scrI[t * 2] + scrI[t * 2 + 1];
                __syncthreads();
            }
        }
    }

    // block-end row-side merge -> packed row slot it + (s - (it>>2))
    const int slot_row = it + (s - (it >> 2));
    if (PASS == 1) {
        float* scrR = (float*)smem;   // A region dead now
        #pragma unroll
        for (int idx = 0; idx < 16; ++idx) {
            float v0 = tp0[idx], v1 = tp1[idx], v2 = tp2[idx], v3 = tp3[idx];
            bmerge(1, v0, v1, v2, v3); bmerge(2, v0, v1, v2, v3);
            bmerge(4, v0, v1, v2, v3); bmerge(8, v0, v1, v2, v3);
            if (lo16 == 0) {
                int rl = wr * 64 + (idx >> 2) * 16 + lg * 4 + (idx & 3);
                float4 st; st.x = v0; st.y = v1; st.z = v2; st.w = v3;
                *(float4*)(scrR + rl * 8 + wc * 4) = st;
            }
        }
        __syncthreads();
        if (t < 128) {
            float4 qa = *(float4*)(scrR + t * 8);
            float4 qb = *(float4*)(scrR + t * 8 + 4);
            float b0 = qa.x, b1 = qa.y, b2 = qa.z, b3 = qa.w;
            ins7(qb.x, b0, b1, b2, b3); ins7(qb.y, b0, b1, b2, b3);
            ins7(qb.z, b0, b1, b2, b3); ins7(qb.w, b0, b1, b2, b3);
            size_t base = ((size_t)(ibase + t) * NS + slot_row) * 4;
            top4p[base + 0] = b0; top4p[base + 1] = b1;
            top4p[base + 2] = b2; top4p[base + 3] = b3;
        }
    } else {
        int* scrI = (int*)smem;
        #pragma unroll
        for (int idx = 0; idx < 16; ++idx) {
            int c = cnt16[idx];
            c += __shfl_xor(c, 1); c += __shfl_xor(c, 2);
            c += __shfl_xor(c, 4); c += __shfl_xor(c, 8);
            if (lo16 == 0) {
                int rl = wr * 64 + (idx >> 2) * 16 + lg * 4 + (idx & 3);
                scrI[rl * 2 + wc] = c;
            }
        }
        __syncthreads();
        if (t < 128) cntp[(size_t)(ibase + t) * NS + slot_row] = scrI[t * 2] + scrI[t * 2 + 1];
    }
}

__global__ void anchor_kernel(const float* __restrict__ top4p, float* __restrict__ anchor) {
    int row = blockIdx.x * 256 + threadIdx.x;
    if (row >= NTOT) return;
    const int p = row >> 7;
    const int nvalid = p + 16 - (p >> 2);   // contiguous valid slots [0, nvalid)
    float b0 = 1e30f, b1 = 1e30f, b2 = 1e30f, b3 = 1e30f;
    const float4* q4 = (const float4*)(top4p + (size_t)row * NS * 4);
    for (int c = 0; c < nvalid; ++c) {
        float4 q = q4[c];
        ins7(q.x, b0, b1, b2, b3); ins7(q.y, b0, b1, b2, b3);
        ins7(q.z, b0, b1, b2, b3); ins7(q.w, b0, b1, b2, b3);
    }
    anchor[row] = b3;
}

// sum count partials -> digamma partial sums; class histogram (320 atomics total)
__global__ void reduce_kernel(const int* __restrict__ cntp, const int* __restrict__ y,
                              float* __restrict__ partials, int* __restrict__ cls) {
    __shared__ float red[256];
    __shared__ int hist[NCLS];
    int t = threadIdx.x;
    if (t < NCLS) hist[t] = 0;
    __syncthreads();
    int row = blockIdx.x * 256 + t;
    const int p = row >> 7;
    const int nvalid = p + 16 - (p >> 2);
    int s = 0;
    for (int c = 0; c < nvalid; ++c) s += cntp[(size_t)row * NS + c];
    atomicAdd(&hist[y[row]], 1);
    red[t] = digammaf_dev((float)(s - 1));
    __syncthreads();
    for (int h = 128; h > 0; h >>= 1) {
        if (t < h) red[t] += red[t + h];
        __syncthreads();
    }
    if (t == 0) partials[blockIdx.x] = red[0];
    if (t < NCLS) atomicAdd(&cls[t], hist[t]);
}

__global__ void finalize_kernel(const float* __restrict__ partials, const int* __restrict__ cls,
                                float* __restrict__ out) {
    if (threadIdx.x == 0) {
        float acc = 0.0f;
        for (int c = 0; c < NTOT / 256; ++c) acc += partials[c];
        float Nf = (float)NTOT;
        float avg_m = acc / Nf;
        float avgNx = 0.0f;
        for (int c = 0; c < NCLS; ++c) {
            float nx = (float)cls[c];
            if (nx > 0.0f) avgNx += (nx / Nf) * digammaf_dev(nx);
        }
        float mi = digammaf_dev(Nf) - avgNx + digammaf_dev(3.0f) - avg_m;
        out[0] = fmaxf(mi / logf(2.0f), 0.0f);
    }
}

extern "C" void kernel_launch(void* const* d_in, const int* in_sizes, int n_in,
                              void* d_out, int out_size, void* d_ws, size_t ws_size,
                              hipStream_t stream) {
    const float* X = (const float*)d_in[0];
    const int* y = (const int*)d_in[1];
    float* out = (float*)d_out;

    float* sq       = (float*)d_ws;                                   // 8192
    float* anchors  = sq + NTOT;                                      // 8192
    float* partials = anchors + NTOT;                                 // 32
    int*   cls      = (int*)(partials + 32);                          // 16
    unsigned short* XS = (unsigned short*)(cls + 16);                 // 8192*256 (4 MB)
    float* top4p    = (float*)(XS + (size_t)NTOT * 256);              // 8192*64*4 (8 MB)
    int*   cntp     = (int*)(top4p + (size_t)NTOT * NS * 4);          // 8192*64 (2 MB)

    zero_kernel<<<1, 64, 0, stream>>>(cls);
    prep_kernel<<<NTOT / 4, 256, 0, stream>>>(X, sq, XS);
    pass_kernel<1><<<NBLKS, 256, 0, stream>>>(XS, y, sq, anchors, top4p, cntp);
    anchor_kernel<<<NTOT / 256, 256, 0, stream>>>(top4p, anchors);
    pass_kernel<2><<<NBLKS, 256, 0, stream>>>(XS, y, sq, anchors, top4p, cntp);
    reduce_kernel<<<NTOT / 256, 256, 0, stream>>>(cntp, y, partials, cls);
    finalize_kernel<<<1, 64, 0, stream>>>(partials, cls, out);
}